// Round 17
// baseline (118.274 us; speedup 1.0000x reference)
//
#include <hip/hip_runtime.h>
#include <hip/hip_bf16.h>
#include <stdint.h>

#define BB   16
#define JJ   256
#define KK   384
#define NROW (BB * JJ)               // 4096
#define NPOS ((size_t)BB * JJ * KK)  // 1572864

// ws layout (bytes)
#define WS_FLAG  0
#define WS_SEL   64                          // int[16*32]
#define WS_VINT  2176                        // int[4096]
#define WS_VBYTE (WS_VINT + NROW * 4)        // int[4096]
#define WS_PART  (WS_VBYTE + NROW * 4)       // float[512][33]
#define WS_REPB  (WS_PART + 512 * 33 * 4)    // float[16][32]

typedef float f32x4 __attribute__((ext_vector_type(4)));
typedef float f32x16 __attribute__((ext_vector_type(16)));
typedef short bf16x8 __attribute__((ext_vector_type(8)));

struct FragU { union { bf16x8 v; uint32_t u[4]; }; };

__device__ __forceinline__ uint32_t rotl32(uint32_t x, int r) {
  return (x << r) | (x >> (32 - r));
}

__device__ __forceinline__ void threefry2x32_k42(uint32_t c0, uint32_t c1,
                                                 uint32_t& o0, uint32_t& o1) {
  const uint32_t ks0 = 0u, ks1 = 42u, ks2 = 0x1BD11BDAu ^ 0u ^ 42u;
  uint32_t x0 = c0 + ks0, x1 = c1 + ks1;
#define TFR(r) { x0 += x1; x1 = rotl32(x1, r); x1 ^= x0; }
  TFR(13) TFR(15) TFR(26) TFR(6)   x0 += ks1; x1 += ks2 + 1u;
  TFR(17) TFR(29) TFR(16) TFR(24)  x0 += ks2; x1 += ks0 + 2u;
  TFR(13) TFR(15) TFR(26) TFR(6)   x0 += ks0; x1 += ks1 + 3u;
  TFR(17) TFR(29) TFR(16) TFR(24)  x0 += ks1; x1 += ks2 + 4u;
  TFR(13) TFR(15) TFR(26) TFR(6)   x0 += ks2; x1 += ks0 + 5u;
#undef TFR
  o0 = x0; o1 = x1;
}

__device__ __forceinline__ uint32_t jax_bits(uint32_t t) {
  uint32_t o0, o1;
  threefry2x32_k42(0u, t, o0, o1);
  return o0 ^ o1;
}

// exact SW-RNE split (setup/one-time use): x ~= hi + lo, both RNE
__device__ __forceinline__ void split2(float x, short& h, short& l) {
  const unsigned short hu = __builtin_bit_cast(unsigned short, __float2bfloat16(x));
  const float hf = __builtin_bit_cast(float, (uint32_t)hu << 16);
  h = (short)hu;
  l = (short)__builtin_bit_cast(unsigned short, __float2bfloat16(x - hf));
}

// FAST activation split: hi = truncated bf16 prefix (v_perm_b32),
// lo = RNE(x - hi) via HW v_cvt_pk_bf16_f32.
__device__ __forceinline__ void split_pk(float x0, float x1,
                                         uint32_t& ph, uint32_t& pl) {
  const uint32_t u0 = __builtin_bit_cast(uint32_t, x0);
  const uint32_t u1 = __builtin_bit_cast(uint32_t, x1);
  ph = __builtin_amdgcn_perm(u1, u0, 0x07060302u);  // hi16(u1):hi16(u0)
  const float r0 = x0 - __builtin_bit_cast(float, u0 & 0xFFFF0000u);
  const float r1 = x1 - __builtin_bit_cast(float, u1 & 0xFFFF0000u);
  uint32_t p;
  asm("v_cvt_pk_bf16_f32 %0, %1, %2" : "=v"(p) : "v"(r0), "v"(r1));
  pl = p;
}

// lane-local refrag for 16x16 path (used by k_image)
__device__ __forceinline__ void refrag_ll(const f32x4 dT0, const f32x4 dT1,
                                          bf16x8& Bh, bf16x8& Bl) {
  FragU H, L;
  split_pk(dT0[0], dT0[1], H.u[0], L.u[0]);
  split_pk(dT0[2], dT0[3], H.u[1], L.u[1]);
  split_pk(dT1[0], dT1[1], H.u[2], L.u[2]);
  split_pk(dT1[2], dT1[3], H.u[3], L.u[3]);
  Bh = H.v; Bl = L.v;
}

__device__ __forceinline__ void refrag_br(f32x4 dT0, f32x4 dT1,
                                          const f32x4 b0, const f32x4 b1,
                                          bf16x8& Bh, bf16x8& Bl) {
#pragma unroll
  for (int r = 0; r < 4; ++r) {
    dT0[r] = fmaxf(dT0[r] + b0[r], 0.f);
    dT1[r] = fmaxf(dT1[r] + b1[r], 0.f);
  }
  refrag_ll(dT0, dT1, Bh, Bl);
}

// 32x32 lane-local refrag: C regs 0..7 -> frag A, 8..15 -> frag B
__device__ __forceinline__ void refrag32(const f32x16& dT,
                                         FragU& HA, FragU& LA,
                                         FragU& HB, FragU& LB) {
  split_pk(dT[0], dT[1], HA.u[0], LA.u[0]);
  split_pk(dT[2], dT[3], HA.u[1], LA.u[1]);
  split_pk(dT[4], dT[5], HA.u[2], LA.u[2]);
  split_pk(dT[6], dT[7], HA.u[3], LA.u[3]);
  split_pk(dT[8], dT[9], HB.u[0], LB.u[0]);
  split_pk(dT[10], dT[11], HB.u[1], LB.u[1]);
  split_pk(dT[12], dT[13], HB.u[2], LB.u[2]);
  split_pk(dT[14], dT[15], HB.u[3], LB.u[3]);
}

// --- 1. row validity under BOTH mask-width interpretations ---
__global__ __launch_bounds__(256) void k_valid(const void* __restrict__ maskp,
                                               int* __restrict__ valid_int,
                                               int* __restrict__ valid_byte) {
  const int row = blockIdx.x * 4 + (threadIdx.x >> 6);
  const int lane = threadIdx.x & 63;
  const uint32_t* wi = (const uint32_t*)maskp + (size_t)row * 384;
  int v = 0;
#pragma unroll
  for (int i = 0; i < 6; ++i) v |= (wi[lane + i * 64] != 0u);
  const unsigned long long bi = __ballot(v);
  const uint32_t* wb = (const uint32_t*)maskp + (size_t)row * 96;
  int u = 0;
  for (int i = lane; i < 96; i += 64) u |= (wb[i] != 0u);
  const unsigned long long bu = __ballot(u);
  if (lane == 0) {
    valid_int[row] = (bi != 0ull) ? 1 : 0;
    valid_byte[row] = (bu != 0ull) ? 1 : 0;
  }
}

// --- 2. detect mask width + per-batch top-S gumbel selection ---
__global__ void k_select(const void* __restrict__ maskp,
                         const int* __restrict__ valid_int,
                         const int* __restrict__ valid_byte,
                         const int* __restrict__ sample_size,
                         int* __restrict__ flag_out, int* __restrict__ sel) {
  const int b = blockIdx.x, lane = threadIdx.x;  // 16 x 64
  const uint32_t* mw = (const uint32_t*)maskp;
  int big = 0;
#pragma unroll
  for (int i = 0; i < 16; ++i) big |= (mw[lane + i * 64] > 1u);
  const int fl = (__ballot(big) != 0ull) ? 1 : 0;
  if (b == 0 && lane == 0) flag_out[0] = fl;
  const int* valid = fl ? valid_byte : valid_int;

  uint32_t comp[4];
#pragma unroll
  for (int q = 0; q < 4; ++q) {
    const int j = lane * 4 + q;
    const uint32_t ub = jax_bits((uint32_t)(b * 256 + j)) >> 9;
    const uint32_t key = valid[b * 256 + j] ? (ub + 1u) : 0u;
    comp[q] = (key << 8) | (uint32_t)(255 - j);  // tie -> smaller j wins
  }
  int S = sample_size[0];
  if (S > 32) S = 32;
  for (int s = 0; s < S; ++s) {
    uint32_t wm = comp[0];
    wm = comp[1] > wm ? comp[1] : wm;
    wm = comp[2] > wm ? comp[2] : wm;
    wm = comp[3] > wm ? comp[3] : wm;
#pragma unroll
    for (int off = 32; off; off >>= 1) {
      const uint32_t o = __shfl_xor(wm, off);
      wm = o > wm ? o : wm;
    }
    if (wm == 0u) {
      if (lane == 0) sel[b * 32 + s] = 0;
    } else {
#pragma unroll
      for (int q = 0; q < 4; ++q) {
        if (comp[q] == wm) {
          sel[b * 32 + s] = 255 - (int)(comp[q] & 0xFFu);
          comp[q] = 0u;
        }
      }
    }
  }
  for (int s2 = S + lane; s2 < 32; s2 += 64) sel[b * 32 + s2] = 0;
}

// --- 3. image branch: zero-LDS swapped MFMA + K-permuted weights (R13) ---
__global__ __launch_bounds__(256, 1) void k_image(
    const float* __restrict__ Imodel, const float* __restrict__ Iobs,
    const float* __restrict__ md, const void* __restrict__ maskp,
    const int* __restrict__ flag, const int* __restrict__ sel,
    const int* __restrict__ sample_size,
    const float* __restrict__ W_in, const float* __restrict__ b_in,
    const float* __restrict__ Wd, const float* __restrict__ bd,
    float* __restrict__ partial) {
  __shared__ float red[4 * 33];
  const int tid = threadIdx.x, wid = tid >> 6, lane = tid & 63;
  const int g = lane >> 4, c = lane & 15;
  const int blk = blockIdx.x;   // 512 = b*32 + s
  const int b = blk >> 5, s = blk & 31;
  const bool active = (s < sample_size[0]);
  const int j = sel[b * 32 + s] & 255;
  const size_t pos0 = ((size_t)(b * JJ + j)) * KK + (size_t)wid * 96;
  const int fl = flag[0];

  bf16x8 AWi[2];
#pragma unroll
  for (int ct = 0; ct < 2; ++ct) {
    short bh, bl; split2(b_in[ct * 16 + c], bh, bl);
#pragma unroll
    for (int e = 0; e < 8; ++e) {
      short v;
      if (g <= 1) {
        short hh, ll; split2(W_in[e * 32 + ct * 16 + c], hh, ll);
        v = hh;
      } else if (g == 2) {
        short hh, ll; split2(W_in[e * 32 + ct * 16 + c], hh, ll);
        v = ll;
      } else {
        v = (e == 0) ? bh : ((e == 1) ? bl : (short)0);
      }
      AWi[ct][e] = v;
    }
  }

  bf16x8 AhW[3][2], AlW[3][2];
#pragma unroll
  for (int d = 0; d < 3; ++d)
#pragma unroll
    for (int ct = 0; ct < 2; ++ct)
#pragma unroll
      for (int e = 0; e < 8; ++e) {
        const int f = (e < 4) ? (4 * g + e) : (16 + 4 * g + (e - 4));
        short hh, ll; split2(Wd[d * 1024 + f * 32 + ct * 16 + c], hh, ll);
        AhW[d][ct][e] = hh; AlW[d][ct][e] = ll;
      }
  f32x4 bsA[3], bsB[3];
#pragma unroll
  for (int d = 0; d < 3; ++d)
#pragma unroll
    for (int r = 0; r < 4; ++r) {
      bsA[d][r] = bd[d * 32 + 4 * g + r];
      bsB[d][r] = bd[d * 32 + 16 + 4 * g + r];
    }

  f32x4 acc0 = {0.f, 0.f, 0.f, 0.f}, acc1 = {0.f, 0.f, 0.f, 0.f};
  float cntv = 0.f;
  const f32x4 z = {0.f, 0.f, 0.f, 0.f};

#pragma unroll 2
  for (int t = 0; t < 6; ++t) {
    const size_t tb = pos0 + (size_t)t * 16;
    const size_t p = tb + c;
    const float i0 = Imodel[p];
    const float i1 = Iobs[p];
    const float* mp = md + p * 6;
    const float2 v0 = *(const float2*)(mp);
    const float2 v1 = *(const float2*)(mp + 2);
    const float2 v2 = *(const float2*)(mp + 4);
    float m;
    if (fl) m = (((const uint8_t*)maskp)[p] != 0) ? 1.f : 0.f;
    else    m = (((const int*)maskp)[p] != 0) ? 1.f : 0.f;
    if (!active) m = 0.f;

    uint32_t ph[4], pl[4];
    split_pk(i0, i1, ph[0], pl[0]);
    split_pk(v0.x, v0.y, ph[1], pl[1]);
    split_pk(v1.x, v1.y, ph[2], pl[2]);
    split_pk(v2.x, v2.y, ph[3], pl[3]);
    FragU Bi;
#pragma unroll
    for (int i = 0; i < 4; ++i) {
      const uint32_t t0 = (g == 1) ? pl[i] : ph[i];
      Bi.u[i] = (g == 3) ? ((i == 0) ? 0x3F803F80u : 0u) : t0;
    }

    f32x4 dT0 = __builtin_amdgcn_mfma_f32_16x16x32_bf16(AWi[0], Bi.v, z, 0, 0, 0);
    f32x4 dT1 = __builtin_amdgcn_mfma_f32_16x16x32_bf16(AWi[1], Bi.v, z, 0, 0, 0);
    bf16x8 Bh, Bl;
    refrag_ll(dT0, dT1, Bh, Bl);

#pragma unroll
    for (int d = 0; d < 3; ++d) {
      dT0 = __builtin_amdgcn_mfma_f32_16x16x32_bf16(AhW[d][0], Bh, z, 0, 0, 0);
      dT1 = __builtin_amdgcn_mfma_f32_16x16x32_bf16(AhW[d][1], Bh, z, 0, 0, 0);
      dT0 = __builtin_amdgcn_mfma_f32_16x16x32_bf16(AlW[d][0], Bh, dT0, 0, 0, 0);
      dT1 = __builtin_amdgcn_mfma_f32_16x16x32_bf16(AlW[d][1], Bh, dT1, 0, 0, 0);
      dT0 = __builtin_amdgcn_mfma_f32_16x16x32_bf16(AhW[d][0], Bl, dT0, 0, 0, 0);
      dT1 = __builtin_amdgcn_mfma_f32_16x16x32_bf16(AhW[d][1], Bl, dT1, 0, 0, 0);
      if (d < 2) {
        refrag_br(dT0, dT1, bsA[d], bsB[d], Bh, Bl);
      } else {
#pragma unroll
        for (int r = 0; r < 4; ++r) {
          acc0[r] = fmaf(m, fmaxf(dT0[r] + bsA[2][r], 0.f), acc0[r]);
          acc1[r] = fmaf(m, fmaxf(dT1[r] + bsB[2][r], 0.f), acc1[r]);
        }
        cntv += m;
      }
    }
  }

#pragma unroll
  for (int off = 1; off < 16; off <<= 1) {
#pragma unroll
    for (int r = 0; r < 4; ++r) {
      acc0[r] += __shfl_xor(acc0[r], off);
      acc1[r] += __shfl_xor(acc1[r], off);
    }
    cntv += __shfl_xor(cntv, off);
  }
  if (c == 0) {
#pragma unroll
    for (int r = 0; r < 4; ++r) {
      red[wid * 33 + 4 * g + r] = acc0[r];
      red[wid * 33 + 16 + 4 * g + r] = acc1[r];
    }
    if (g == 0) red[wid * 33 + 32] = cntv;
  }
  __syncthreads();
  if (tid < 33) {
    partial[blk * 33 + tid] =
        red[tid] + red[33 + tid] + red[66 + tid] + red[99 + tid];
  }
}

// --- 4. reduce partials -> rep_bias[b][n] = b_lin[n] + sum/cnt ---
__global__ void k_rep(const float* __restrict__ partial,
                      const float* __restrict__ b_lin,
                      float* __restrict__ rep_bias) {
  const int b = blockIdx.x, n = threadIdx.x;  // 16 x 32
  float sum = 0.f, cnt = 0.f;
  for (int s = 0; s < 32; ++s) {
    sum += partial[(b * 32 + s) * 33 + n];
    cnt += partial[(b * 32 + s) * 33 + 32];
  }
  rep_bias[b * 32 + n] = b_lin[n] + sum / cnt;
}

// --- 5. main pass: 32x32x16 MFMA + 2-tile ILP; __launch_bounds__(256,3)
//     (164 total regs fits the 170 budget -> 3 waves/SIMD) ---
__global__ __launch_bounds__(256, 3) void k_scale(
    const float* __restrict__ md, const void* __restrict__ maskp,
    const int* __restrict__ flag,
    const float* __restrict__ W_lin, const float* __restrict__ rep_bias,
    const float* __restrict__ Wd, const float* __restrict__ bd,
    const float* __restrict__ W_out, const float* __restrict__ b_out,
    float* __restrict__ out) {
  const int tid = threadIdx.x;
  const int wid = tid >> 6, lane = tid & 63;
  const int p = lane & 31, h = lane >> 5;
  const int job = blockIdx.x * 4 + wid;       // 6144 jobs x 256 positions
  const int b = job / 384;
  const size_t pos0 = (size_t)job * 256;
  const int fl = flag[0];

  // input-layer A-frag: row=out-feat(lane&31); k: h=0 -> Wh ch0-5 + rb_h,rb_l;
  // h=1 -> Wl ch0-5 + 0,0
  bf16x8 AW;
  {
    short rbh, rbl; split2(rep_bias[b * 32 + p], rbh, rbl);
#pragma unroll
    for (int e = 0; e < 8; ++e) {
      short v = 0;
      if (e < 6) {
        short wh, wl; split2(W_lin[e * 32 + p], wh, wl);
        v = h ? wl : wh;
      } else if (h == 0) {
        v = (e == 6) ? rbh : rbl;
      }
      AW[e] = v;
    }
  }

  // hidden-layer A-frags, K-permuted
  bf16x8 Ah[3][2], Al[3][2];
#pragma unroll
  for (int d = 0; d < 3; ++d)
#pragma unroll
    for (int m = 0; m < 2; ++m)
#pragma unroll
      for (int e = 0; e < 8; ++e) {
        const int f = ((e < 4) ? e : (e + 4)) + 4 * h + 16 * m;
        short hh, ll; split2(Wd[d * 1024 + f * 32 + p], hh, ll);
        Ah[d][m][e] = hh; Al[d][m][e] = ll;
      }
  f32x4 bs[3][4], wo[4];
#pragma unroll
  for (int q4 = 0; q4 < 4; ++q4)
#pragma unroll
    for (int r = 0; r < 4; ++r) {
      const int f = r + 8 * q4 + 4 * h;
#pragma unroll
      for (int d = 0; d < 3; ++d) bs[d][q4][r] = bd[d * 32 + f];
      wo[q4][r] = W_out[f];
    }
  const float bo = b_out[0];
  const uint32_t ones_word = (h == 0) ? 0x3F803F80u : 0u;

  const float* mdp = md + (pos0 + p) * 6;
  const uint8_t* mb8 = (const uint8_t*)maskp + pos0 + p;
  const uint32_t* mb32 = (const uint32_t*)maskp + pos0 + p;
  const f32x16 z16 = {0.f,0.f,0.f,0.f,0.f,0.f,0.f,0.f,
                      0.f,0.f,0.f,0.f,0.f,0.f,0.f,0.f};

  // prefetch pair 0 (tiles 0,1)
  float2 a01A = *(const float2*)(mdp);
  float2 a23A = *(const float2*)(mdp + 2);
  float2 a45A = *(const float2*)(mdp + 4);
  float2 a01B = *(const float2*)(mdp + 192);
  float2 a23B = *(const float2*)(mdp + 194);
  float2 a45B = *(const float2*)(mdp + 196);
  uint32_t mkA = fl ? (uint32_t)mb8[0] : mb32[0];
  uint32_t mkB = fl ? (uint32_t)mb8[32] : mb32[32];

  for (int t = 0; t < 4; ++t) {                // 4 pairs of 32-pos tiles
    const size_t tbA = pos0 + (size_t)t * 64;
    const size_t tbB = tbA + 32;

    float2 n01A = {0,0}, n23A = {0,0}, n45A = {0,0};
    float2 n01B = {0,0}, n23B = {0,0}, n45B = {0,0};
    uint32_t nkA = 0, nkB = 0;
    if (t < 3) {
      const float* nrA = mdp + (2 * t + 2) * 192;
      n01A = *(const float2*)(nrA);
      n23A = *(const float2*)(nrA + 2);
      n45A = *(const float2*)(nrA + 4);
      const float* nrB = mdp + (2 * t + 3) * 192;
      n01B = *(const float2*)(nrB);
      n23B = *(const float2*)(nrB + 2);
      n45B = *(const float2*)(nrB + 4);
      nkA = fl ? (uint32_t)mb8[(2 * t + 2) * 32] : mb32[(2 * t + 2) * 32];
      nkB = fl ? (uint32_t)mb8[(2 * t + 3) * 32] : mb32[(2 * t + 3) * 32];
    }

    FragU B1A, B2A, B1B, B2B;
    {
      uint32_t ph0, pl0, ph1, pl1, ph2, pl2;
      split_pk(a01A.x, a01A.y, ph0, pl0);
      split_pk(a23A.x, a23A.y, ph1, pl1);
      split_pk(a45A.x, a45A.y, ph2, pl2);
      B1A.u[0] = ph0; B1A.u[1] = ph1; B1A.u[2] = ph2; B1A.u[3] = ones_word;
      B2A.u[0] = pl0; B2A.u[1] = pl1; B2A.u[2] = pl2; B2A.u[3] = 0u;
      split_pk(a01B.x, a01B.y, ph0, pl0);
      split_pk(a23B.x, a23B.y, ph1, pl1);
      split_pk(a45B.x, a45B.y, ph2, pl2);
      B1B.u[0] = ph0; B1B.u[1] = ph1; B1B.u[2] = ph2; B1B.u[3] = ones_word;
      B2B.u[0] = pl0; B2B.u[1] = pl1; B2B.u[2] = pl2; B2B.u[3] = 0u;
    }

    f32x16 dTA = __builtin_amdgcn_mfma_f32_32x32x16_bf16(AW, B1A.v, z16, 0, 0, 0);
    f32x16 dTB = __builtin_amdgcn_mfma_f32_32x32x16_bf16(AW, B1B.v, z16, 0, 0, 0);
    dTA = __builtin_amdgcn_mfma_f32_32x32x16_bf16(AW, B2A.v, dTA, 0, 0, 0);
    dTB = __builtin_amdgcn_mfma_f32_32x32x16_bf16(AW, B2B.v, dTB, 0, 0, 0);

    FragU HAA, LAA, HBA, LBA;   // tile A frags
    FragU HAB, LAB, HBB, LBB;   // tile B frags
    refrag32(dTA, HAA, LAA, HBA, LBA);
    refrag32(dTB, HAB, LAB, HBB, LBB);

#pragma unroll
    for (int d = 0; d < 3; ++d) {
      f32x16 nTA = __builtin_amdgcn_mfma_f32_32x32x16_bf16(Ah[d][0], HAA.v, z16, 0, 0, 0);
      f32x16 nTB = __builtin_amdgcn_mfma_f32_32x32x16_bf16(Ah[d][0], HAB.v, z16, 0, 0, 0);
      nTA = __builtin_amdgcn_mfma_f32_32x32x16_bf16(Ah[d][1], HBA.v, nTA, 0, 0, 0);
      nTB = __builtin_amdgcn_mfma_f32_32x32x16_bf16(Ah[d][1], HBB.v, nTB, 0, 0, 0);
      nTA = __builtin_amdgcn_mfma_f32_32x32x16_bf16(Al[d][0], HAA.v, nTA, 0, 0, 0);
      nTB = __builtin_amdgcn_mfma_f32_32x32x16_bf16(Al[d][0], HAB.v, nTB, 0, 0, 0);
      nTA = __builtin_amdgcn_mfma_f32_32x32x16_bf16(Al[d][1], HBA.v, nTA, 0, 0, 0);
      nTB = __builtin_amdgcn_mfma_f32_32x32x16_bf16(Al[d][1], HBB.v, nTB, 0, 0, 0);
      nTA = __builtin_amdgcn_mfma_f32_32x32x16_bf16(Ah[d][0], LAA.v, nTA, 0, 0, 0);
      nTB = __builtin_amdgcn_mfma_f32_32x32x16_bf16(Ah[d][0], LAB.v, nTB, 0, 0, 0);
      nTA = __builtin_amdgcn_mfma_f32_32x32x16_bf16(Ah[d][1], LBA.v, nTA, 0, 0, 0);
      nTB = __builtin_amdgcn_mfma_f32_32x32x16_bf16(Ah[d][1], LBB.v, nTB, 0, 0, 0);
      if (d < 2) {
        float xA[16], xB[16];
#pragma unroll
        for (int q4 = 0; q4 < 4; ++q4)
#pragma unroll
          for (int r = 0; r < 4; ++r) {
            xA[q4 * 4 + r] = fmaxf(nTA[q4 * 4 + r] + bs[d][q4][r], 0.f);
            xB[q4 * 4 + r] = fmaxf(nTB[q4 * 4 + r] + bs[d][q4][r], 0.f);
          }
        split_pk(xA[0], xA[1], HAA.u[0], LAA.u[0]);
        split_pk(xA[2], xA[3], HAA.u[1], LAA.u[1]);
        split_pk(xA[4], xA[5], HAA.u[2], LAA.u[2]);
        split_pk(xA[6], xA[7], HAA.u[3], LAA.u[3]);
        split_pk(xA[8], xA[9], HBA.u[0], LBA.u[0]);
        split_pk(xA[10], xA[11], HBA.u[1], LBA.u[1]);
        split_pk(xA[12], xA[13], HBA.u[2], LBA.u[2]);
        split_pk(xA[14], xA[15], HBA.u[3], LBA.u[3]);
        split_pk(xB[0], xB[1], HAB.u[0], LAB.u[0]);
        split_pk(xB[2], xB[3], HAB.u[1], LAB.u[1]);
        split_pk(xB[4], xB[5], HAB.u[2], LAB.u[2]);
        split_pk(xB[6], xB[7], HAB.u[3], LAB.u[3]);
        split_pk(xB[8], xB[9], HBB.u[0], LBB.u[0]);
        split_pk(xB[10], xB[11], HBB.u[1], LBB.u[1]);
        split_pk(xB[12], xB[13], HBB.u[2], LBB.u[2]);
        split_pk(xB[14], xB[15], HBB.u[3], LBB.u[3]);
      } else {
        float sumA = 0.f, sumB = 0.f;
#pragma unroll
        for (int q4 = 0; q4 < 4; ++q4)
#pragma unroll
          for (int r = 0; r < 4; ++r) {
            sumA = fmaf(fmaxf(nTA[q4 * 4 + r] + bs[2][q4][r], 0.f),
                        wo[q4][r], sumA);
            sumB = fmaf(fmaxf(nTB[q4 * 4 + r] + bs[2][q4][r], 0.f),
                        wo[q4][r], sumB);
          }
        sumA += __shfl_xor(sumA, 32);
        sumB += __shfl_xor(sumB, 32);
        if (h == 0) {
          out[tbA + p] = mkA ? (sumA + bo) : 0.0f;
          out[tbB + p] = mkB ? (sumB + bo) : 0.0f;
        }
      }
    }

    a01A = n01A; a23A = n23A; a45A = n45A;
    a01B = n01B; a23B = n23B; a45B = n45B;
    mkA = nkA; mkB = nkB;
  }
}

extern "C" void kernel_launch(void* const* d_in, const int* in_sizes, int n_in,
                              void* d_out, int out_size, void* d_ws, size_t ws_size,
                              hipStream_t stream) {
  const float* Imodel   = (const float*)d_in[0];
  const float* Iobs     = (const float*)d_in[1];
  const float* metadata = (const float*)d_in[2];
  const void*  mask     = d_in[3];
  const int*   sample_size = (const int*)d_in[4];
  const float* W_img_in = (const float*)d_in[5];
  const float* b_img_in = (const float*)d_in[6];
  const float* W_img    = (const float*)d_in[7];
  const float* b_img    = (const float*)d_in[8];
  const float* W_lin_in = (const float*)d_in[9];
  const float* b_lin_in = (const float*)d_in[10];
  const float* W_mlp    = (const float*)d_in[11];
  const float* b_mlp    = (const float*)d_in[12];
  const float* W_out    = (const float*)d_in[13];
  const float* b_out    = (const float*)d_in[14];
  float* out = (float*)d_out;

  char* ws = (char*)d_ws;
  int*   flag     = (int*)(ws + WS_FLAG);
  int*   sel      = (int*)(ws + WS_SEL);
  int*   vint     = (int*)(ws + WS_VINT);
  int*   vbyte    = (int*)(ws + WS_VBYTE);
  float* partial  = (float*)(ws + WS_PART);
  float* rep_bias = (float*)(ws + WS_REPB);

  k_valid<<<NROW / 4, 256, 0, stream>>>(mask, vint, vbyte);
  k_select<<<BB, 64, 0, stream>>>(mask, vint, vbyte, sample_size, flag, sel);
  k_image<<<512, 256, 0, stream>>>(Imodel, Iobs, metadata, mask, flag, sel,
                                   sample_size, W_img_in, b_img_in, W_img,
                                   b_img, partial);
  k_rep<<<BB, 32, 0, stream>>>(partial, b_lin_in, rep_bias);
  k_scale<<<1536, 256, 0, stream>>>(metadata, mask, flag, W_lin_in, rep_bias,
                                    W_mlp, b_mlp, W_out, b_out, out);
}

// Round 18
// 77.491 us; speedup vs baseline: 1.5263x; 1.5263x over previous
//
#include <hip/hip_runtime.h>
#include <hip/hip_bf16.h>
#include <stdint.h>

#define BB   16
#define JJ   256
#define KK   384
#define NROW (BB * JJ)               // 4096
#define NPOS ((size_t)BB * JJ * KK)  // 1572864

// ws layout (bytes)
#define WS_FLAG  0
#define WS_SEL   64                          // int[16*32]
#define WS_VINT  2176                        // int[4096]
#define WS_VBYTE (WS_VINT + NROW * 4)        // int[4096]
#define WS_PART  (WS_VBYTE + NROW * 4)       // float[512][33]
#define WS_REPB  (WS_PART + 512 * 33 * 4)    // float[16][32]

typedef float f32x4 __attribute__((ext_vector_type(4)));
typedef short bf16x8 __attribute__((ext_vector_type(8)));

struct FragU { union { bf16x8 v; uint32_t u[4]; }; };

__device__ __forceinline__ uint32_t rotl32(uint32_t x, int r) {
  return (x << r) | (x >> (32 - r));
}

__device__ __forceinline__ void threefry2x32_k42(uint32_t c0, uint32_t c1,
                                                 uint32_t& o0, uint32_t& o1) {
  const uint32_t ks0 = 0u, ks1 = 42u, ks2 = 0x1BD11BDAu ^ 0u ^ 42u;
  uint32_t x0 = c0 + ks0, x1 = c1 + ks1;
#define TFR(r) { x0 += x1; x1 = rotl32(x1, r); x1 ^= x0; }
  TFR(13) TFR(15) TFR(26) TFR(6)   x0 += ks1; x1 += ks2 + 1u;
  TFR(17) TFR(29) TFR(16) TFR(24)  x0 += ks2; x1 += ks0 + 2u;
  TFR(13) TFR(15) TFR(26) TFR(6)   x0 += ks0; x1 += ks1 + 3u;
  TFR(17) TFR(29) TFR(16) TFR(24)  x0 += ks1; x1 += ks2 + 4u;
  TFR(13) TFR(15) TFR(26) TFR(6)   x0 += ks2; x1 += ks0 + 5u;
#undef TFR
  o0 = x0; o1 = x1;
}

__device__ __forceinline__ uint32_t jax_bits(uint32_t t) {
  uint32_t o0, o1;
  threefry2x32_k42(0u, t, o0, o1);
  return o0 ^ o1;
}

// exact SW-RNE split (setup/one-time use): x ~= hi + lo, both RNE
__device__ __forceinline__ void split2(float x, short& h, short& l) {
  const unsigned short hu = __builtin_bit_cast(unsigned short, __float2bfloat16(x));
  const float hf = __builtin_bit_cast(float, (uint32_t)hu << 16);
  h = (short)hu;
  l = (short)__builtin_bit_cast(unsigned short, __float2bfloat16(x - hf));
}

// FAST activation split (hot loop): hi = truncated bf16 prefix (v_perm_b32),
// lo = RNE(x - hi) via HW v_cvt_pk_bf16_f32.
__device__ __forceinline__ void split_pk(float x0, float x1,
                                         uint32_t& ph, uint32_t& pl) {
  const uint32_t u0 = __builtin_bit_cast(uint32_t, x0);
  const uint32_t u1 = __builtin_bit_cast(uint32_t, x1);
  ph = __builtin_amdgcn_perm(u1, u0, 0x07060302u);  // hi16(u1):hi16(u0)
  const float r0 = x0 - __builtin_bit_cast(float, u0 & 0xFFFF0000u);
  const float r1 = x1 - __builtin_bit_cast(float, u1 & 0xFFFF0000u);
  uint32_t p;
  asm("v_cvt_pk_bf16_f32 %0, %1, %2" : "=v"(p) : "v"(r0), "v"(r1));
  pl = p;
}

// lane-local refrag (K-permuted layout): Bh/Bl slots e<4 <- dT0, e>=4 <- dT1
__device__ __forceinline__ void refrag_ll(const f32x4 dT0, const f32x4 dT1,
                                          bf16x8& Bh, bf16x8& Bl) {
  FragU H, L;
  split_pk(dT0[0], dT0[1], H.u[0], L.u[0]);
  split_pk(dT0[2], dT0[3], H.u[1], L.u[1]);
  split_pk(dT1[0], dT1[1], H.u[2], L.u[2]);
  split_pk(dT1[2], dT1[3], H.u[3], L.u[3]);
  Bh = H.v; Bl = L.v;
}

__device__ __forceinline__ void refrag_br(f32x4 dT0, f32x4 dT1,
                                          const f32x4 b0, const f32x4 b1,
                                          bf16x8& Bh, bf16x8& Bl) {
#pragma unroll
  for (int r = 0; r < 4; ++r) {
    dT0[r] = fmaxf(dT0[r] + b0[r], 0.f);
    dT1[r] = fmaxf(dT1[r] + b1[r], 0.f);
  }
  refrag_ll(dT0, dT1, Bh, Bl);
}

// --- 1. row validity under BOTH mask-width interpretations ---
__global__ __launch_bounds__(256) void k_valid(const void* __restrict__ maskp,
                                               int* __restrict__ valid_int,
                                               int* __restrict__ valid_byte) {
  const int row = blockIdx.x * 4 + (threadIdx.x >> 6);
  const int lane = threadIdx.x & 63;
  const uint32_t* wi = (const uint32_t*)maskp + (size_t)row * 384;
  int v = 0;
#pragma unroll
  for (int i = 0; i < 6; ++i) v |= (wi[lane + i * 64] != 0u);
  const unsigned long long bi = __ballot(v);
  const uint32_t* wb = (const uint32_t*)maskp + (size_t)row * 96;
  int u = 0;
  for (int i = lane; i < 96; i += 64) u |= (wb[i] != 0u);
  const unsigned long long bu = __ballot(u);
  if (lane == 0) {
    valid_int[row] = (bi != 0ull) ? 1 : 0;
    valid_byte[row] = (bu != 0ull) ? 1 : 0;
  }
}

// --- 2. detect mask width + per-batch top-S gumbel selection ---
__global__ void k_select(const void* __restrict__ maskp,
                         const int* __restrict__ valid_int,
                         const int* __restrict__ valid_byte,
                         const int* __restrict__ sample_size,
                         int* __restrict__ flag_out, int* __restrict__ sel) {
  const int b = blockIdx.x, lane = threadIdx.x;  // 16 x 64
  const uint32_t* mw = (const uint32_t*)maskp;
  int big = 0;
#pragma unroll
  for (int i = 0; i < 16; ++i) big |= (mw[lane + i * 64] > 1u);
  const int fl = (__ballot(big) != 0ull) ? 1 : 0;
  if (b == 0 && lane == 0) flag_out[0] = fl;
  const int* valid = fl ? valid_byte : valid_int;

  uint32_t comp[4];
#pragma unroll
  for (int q = 0; q < 4; ++q) {
    const int j = lane * 4 + q;
    const uint32_t ub = jax_bits((uint32_t)(b * 256 + j)) >> 9;
    const uint32_t key = valid[b * 256 + j] ? (ub + 1u) : 0u;
    comp[q] = (key << 8) | (uint32_t)(255 - j);  // tie -> smaller j wins
  }
  int S = sample_size[0];
  if (S > 32) S = 32;
  for (int s = 0; s < S; ++s) {
    uint32_t wm = comp[0];
    wm = comp[1] > wm ? comp[1] : wm;
    wm = comp[2] > wm ? comp[2] : wm;
    wm = comp[3] > wm ? comp[3] : wm;
#pragma unroll
    for (int off = 32; off; off >>= 1) {
      const uint32_t o = __shfl_xor(wm, off);
      wm = o > wm ? o : wm;
    }
    if (wm == 0u) {
      if (lane == 0) sel[b * 32 + s] = 0;
    } else {
#pragma unroll
      for (int q = 0; q < 4; ++q) {
        if (comp[q] == wm) {
          sel[b * 32 + s] = 255 - (int)(comp[q] & 0xFFu);
          comp[q] = 0u;
        }
      }
    }
  }
  for (int s2 = S + lane; s2 < 32; s2 += 64) sel[b * 32 + s2] = 0;
}

// --- 3. image branch via split-bf16 MFMA (proven R5-era version) ---
__global__ __launch_bounds__(256, 1) void k_image(
    const float* __restrict__ Imodel, const float* __restrict__ Iobs,
    const float* __restrict__ md, const void* __restrict__ maskp,
    const int* __restrict__ flag, const int* __restrict__ sel,
    const int* __restrict__ sample_size,
    const float* __restrict__ W_in, const float* __restrict__ b_in,
    const float* __restrict__ Wd, const float* __restrict__ bd,
    float* __restrict__ partial) {
  __shared__ float lds_t[4][16 * 36];
  __shared__ float red[4 * 33];
  const int tid = threadIdx.x, wid = tid >> 6, lane = tid & 63;
  const int g = lane >> 4, c = lane & 15;
  const int blk = blockIdx.x;   // 512 = b*32 + s
  const int b = blk >> 5, s = blk & 31;
  const bool active = (s < sample_size[0]);
  const int j = sel[b * 32 + s] & 255;
  const size_t pos0 = ((size_t)(b * JJ + j)) * KK + (size_t)wid * 96;
  const int fl = flag[0];

  float Win[8][8];
#pragma unroll
  for (int cc = 0; cc < 8; ++cc)
#pragma unroll
    for (int e = 0; e < 8; ++e) Win[cc][e] = W_in[cc * 32 + g * 8 + e];
  float b0v[8];
#pragma unroll
  for (int e = 0; e < 8; ++e) b0v[e] = b_in[g * 8 + e];

  bf16x8 Bh[3][2], Bl[3][2];
#pragma unroll
  for (int d = 0; d < 3; ++d)
#pragma unroll
    for (int ct = 0; ct < 2; ++ct)
#pragma unroll
      for (int e = 0; e < 8; ++e) {
        const float w = Wd[d * 1024 + (g * 8 + e) * 32 + ct * 16 + c];
        short hh, ll; split2(w, hh, ll);
        Bh[d][ct][e] = hh; Bl[d][ct][e] = ll;
      }
  float bias_v[3][2];
#pragma unroll
  for (int d = 0; d < 3; ++d) {
    bias_v[d][0] = bd[d * 32 + c];
    bias_v[d][1] = bd[d * 32 + 16 + c];
  }
  float* myl = lds_t[wid];

  float acc0 = 0.f, acc1 = 0.f, cntv = 0.f;

  for (int t = 0; t < 6; ++t) {
    const size_t tb = pos0 + (size_t)t * 16;
    const size_t p = tb + c;
    float in[8];
    in[0] = Imodel[p];
    in[1] = Iobs[p];
    const float* mp = md + p * 6;
    const float2 v0 = *(const float2*)(mp);
    const float2 v1 = *(const float2*)(mp + 2);
    const float2 v2 = *(const float2*)(mp + 4);
    in[2] = v0.x; in[3] = v0.y; in[4] = v1.x; in[5] = v1.y;
    in[6] = v2.x; in[7] = v2.y;

    bf16x8 ah, al;
#pragma unroll
    for (int e = 0; e < 8; ++e) {
      float h = b0v[e];
#pragma unroll
      for (int cc = 0; cc < 8; ++cc) h = fmaf(in[cc], Win[cc][e], h);
      short hh, ll; split2(h, hh, ll);
      ah[e] = hh; al[e] = ll;
    }

#pragma unroll
    for (int d = 0; d < 3; ++d) {
      f32x4 a0 = {0.f, 0.f, 0.f, 0.f}, a1 = {0.f, 0.f, 0.f, 0.f};
      a0 = __builtin_amdgcn_mfma_f32_16x16x32_bf16(ah, Bh[d][0], a0, 0, 0, 0);
      a0 = __builtin_amdgcn_mfma_f32_16x16x32_bf16(al, Bh[d][0], a0, 0, 0, 0);
      a0 = __builtin_amdgcn_mfma_f32_16x16x32_bf16(ah, Bl[d][0], a0, 0, 0, 0);
      a1 = __builtin_amdgcn_mfma_f32_16x16x32_bf16(ah, Bh[d][1], a1, 0, 0, 0);
      a1 = __builtin_amdgcn_mfma_f32_16x16x32_bf16(al, Bh[d][1], a1, 0, 0, 0);
      a1 = __builtin_amdgcn_mfma_f32_16x16x32_bf16(ah, Bl[d][1], a1, 0, 0, 0);
#pragma unroll
      for (int r = 0; r < 4; ++r) {
        a0[r] = fmaxf(a0[r] + bias_v[d][0], 0.f);
        a1[r] = fmaxf(a1[r] + bias_v[d][1], 0.f);
      }
      if (d < 2) {
#pragma unroll
        for (int r = 0; r < 4; ++r) {
          myl[(g * 4 + r) * 36 + c] = a0[r];
          myl[(g * 4 + r) * 36 + 16 + c] = a1[r];
        }
#pragma unroll
        for (int e = 0; e < 8; ++e) {
          const float h = myl[c * 36 + g * 8 + e];
          short hh, ll; split2(h, hh, ll);
          ah[e] = hh; al[e] = ll;
        }
      } else {
        float mr[4];
        if (fl) {
          const uint32_t mw = *(const uint32_t*)((const uint8_t*)maskp + tb + g * 4);
          mr[0] = (mw & 0x000000FFu) ? 1.f : 0.f;
          mr[1] = (mw & 0x0000FF00u) ? 1.f : 0.f;
          mr[2] = (mw & 0x00FF0000u) ? 1.f : 0.f;
          mr[3] = (mw & 0xFF000000u) ? 1.f : 0.f;
        } else {
          const int4 mi = *(const int4*)((const int*)maskp + tb + g * 4);
          mr[0] = mi.x ? 1.f : 0.f;
          mr[1] = mi.y ? 1.f : 0.f;
          mr[2] = mi.z ? 1.f : 0.f;
          mr[3] = mi.w ? 1.f : 0.f;
        }
        if (!active) { mr[0] = mr[1] = mr[2] = mr[3] = 0.f; }
#pragma unroll
        for (int r = 0; r < 4; ++r) {
          acc0 = fmaf(mr[r], a0[r], acc0);
          acc1 = fmaf(mr[r], a1[r], acc1);
          cntv += mr[r];
        }
      }
    }
  }

  acc0 += __shfl_xor(acc0, 16); acc0 += __shfl_xor(acc0, 32);
  acc1 += __shfl_xor(acc1, 16); acc1 += __shfl_xor(acc1, 32);
  cntv += __shfl_xor(cntv, 16); cntv += __shfl_xor(cntv, 32);
  if (lane < 16) {
    red[wid * 33 + lane] = acc0;
    red[wid * 33 + 16 + lane] = acc1;
  }
  if (lane == 0) red[wid * 33 + 32] = cntv;
  __syncthreads();
  if (tid < 33) {
    partial[blk * 33 + tid] =
        red[tid] + red[33 + tid] + red[66 + tid] + red[99 + tid];
  }
}

// --- 4. reduce partials -> rep_bias[b][n] = b_lin[n] + sum/cnt ---
__global__ void k_rep(const float* __restrict__ partial,
                      const float* __restrict__ b_lin,
                      float* __restrict__ rep_bias) {
  const int b = blockIdx.x, n = threadIdx.x;  // 16 x 32
  float sum = 0.f, cnt = 0.f;
  for (int s = 0; s < 32; ++s) {
    sum += partial[(b * 32 + s) * 33 + n];
    cnt += partial[(b * 32 + s) * 33 + 32];
  }
  rep_bias[b * 32 + n] = b_lin[n] + sum / cnt;
}

// --- 5. main pass: swapped MFMA + K-permuted weights, 2-tile ILP,
//     HW activation splits (best measured config: R12 bench, 49.7 us) ---
__global__ __launch_bounds__(256, 3) void k_scale(
    const float* __restrict__ md, const void* __restrict__ maskp,
    const int* __restrict__ flag,
    const float* __restrict__ W_lin, const float* __restrict__ rep_bias,
    const float* __restrict__ Wd, const float* __restrict__ bd,
    const float* __restrict__ W_out, const float* __restrict__ b_out,
    float* __restrict__ out) {
  const int tid = threadIdx.x;
  const int wid = tid >> 6, lane = tid & 63;
  const int g = lane >> 4, c = lane & 15;
  const int job = blockIdx.x * 4 + wid;       // 6144 jobs x 256 positions
  const int b = job / 384;
  const size_t pos0 = (size_t)job * 256;
  const int fl = flag[0];
  const bool gLt2 = (g < 2);

  // input-layer A-frags (channels 0-5 + rep_bias in k-slots 6,7)
  bf16x8 AW[2];
#pragma unroll
  for (int ct = 0; ct < 2; ++ct) {
    const float rb = rep_bias[b * 32 + ct * 16 + c];
    short rbh, rbl; split2(rb, rbh, rbl);
#pragma unroll
    for (int e = 0; e < 8; ++e) {
      short v = 0;
      if (e < 6) {
        short wh, wl; split2(W_lin[e * 32 + ct * 16 + c], wh, wl);
        v = gLt2 ? wh : wl;
      } else if (g == 0) {
        v = (e == 6) ? rbh : rbl;
      }
      AW[ct][e] = v;
    }
  }

  // hidden-layer A-frags with permuted K: slot (g,e) <- feat finv(g,e)
  bf16x8 AhW[3][2], AlW[3][2];
#pragma unroll
  for (int d = 0; d < 3; ++d)
#pragma unroll
    for (int ct = 0; ct < 2; ++ct)
#pragma unroll
      for (int e = 0; e < 8; ++e) {
        const int f = (e < 4) ? (4 * g + e) : (16 + 4 * g + (e - 4));
        short hh, ll; split2(Wd[d * 1024 + f * 32 + ct * 16 + c], hh, ll);
        AhW[d][ct][e] = hh; AlW[d][ct][e] = ll;
      }
  f32x4 bsA[3], bsB[3];
#pragma unroll
  for (int d = 0; d < 3; ++d)
#pragma unroll
    for (int r = 0; r < 4; ++r) {
      bsA[d][r] = bd[d * 32 + 4 * g + r];
      bsB[d][r] = bd[d * 32 + 16 + 4 * g + r];
    }
  f32x4 woA, woB;
#pragma unroll
  for (int r = 0; r < 4; ++r) {
    woA[r] = W_out[4 * g + r];
    woB[r] = W_out[16 + 4 * g + r];
  }
  const float bo = b_out[0];
  const uint32_t bias_word = (g == 0) ? 0x00003F80u : 0u;

  // prefetch pair 0 (tiles 0,1)
  float mvA[6], mvB[6];
  uint32_t mkA, mkB;
  {
    const float* ra = md + (pos0 + c) * 6;
    const float2 a01 = *(const float2*)(ra);
    const float2 a23 = *(const float2*)(ra + 2);
    const float2 a45 = *(const float2*)(ra + 4);
    mvA[0] = a01.x; mvA[1] = a01.y; mvA[2] = a23.x;
    mvA[3] = a23.y; mvA[4] = a45.x; mvA[5] = a45.y;
    const float* rb2 = md + (pos0 + 16 + c) * 6;
    const float2 b01 = *(const float2*)(rb2);
    const float2 b23 = *(const float2*)(rb2 + 2);
    const float2 b45 = *(const float2*)(rb2 + 4);
    mvB[0] = b01.x; mvB[1] = b01.y; mvB[2] = b23.x;
    mvB[3] = b23.y; mvB[4] = b45.x; mvB[5] = b45.y;
    if (fl) {
      mkA = (uint32_t)((const uint8_t*)maskp)[pos0 + c];
      mkB = (uint32_t)((const uint8_t*)maskp)[pos0 + 16 + c];
    } else {
      mkA = ((const uint32_t*)maskp)[pos0 + c];
      mkB = ((const uint32_t*)maskp)[pos0 + 16 + c];
    }
  }

  const f32x4 z = {0.f, 0.f, 0.f, 0.f};

  for (int tp = 0; tp < 8; ++tp) {
    const size_t tbA = pos0 + (size_t)tp * 32;
    const size_t tbB = tbA + 16;

    // prefetch next pair (hidden under this pair's compute)
    float nvA[6] = {0, 0, 0, 0, 0, 0}, nvB[6] = {0, 0, 0, 0, 0, 0};
    uint32_t nkA = 0, nkB = 0;
    if (tp < 7) {
      const float* ra = md + (tbA + 32 + c) * 6;
      const float2 a01 = *(const float2*)(ra);
      const float2 a23 = *(const float2*)(ra + 2);
      const float2 a45 = *(const float2*)(ra + 4);
      nvA[0] = a01.x; nvA[1] = a01.y; nvA[2] = a23.x;
      nvA[3] = a23.y; nvA[4] = a45.x; nvA[5] = a45.y;
      const float* rb2 = md + (tbA + 48 + c) * 6;
      const float2 b01 = *(const float2*)(rb2);
      const float2 b23 = *(const float2*)(rb2 + 2);
      const float2 b45 = *(const float2*)(rb2 + 4);
      nvB[0] = b01.x; nvB[1] = b01.y; nvB[2] = b23.x;
      nvB[3] = b23.y; nvB[4] = b45.x; nvB[5] = b45.y;
      if (fl) {
        nkA = (uint32_t)((const uint8_t*)maskp)[tbA + 32 + c];
        nkB = (uint32_t)((const uint8_t*)maskp)[tbA + 48 + c];
      } else {
        nkA = ((const uint32_t*)maskp)[tbA + 32 + c];
        nkB = ((const uint32_t*)maskp)[tbA + 48 + c];
      }
    }

    // B-frags for both tiles: words 0-2 hi/lo packed pairs by (g&1), w3 bias
    FragU BinA, BinB;
    {
      uint32_t ph0, pl0, ph1, pl1, ph2, pl2;
      split_pk(mvA[0], mvA[1], ph0, pl0);
      split_pk(mvA[2], mvA[3], ph1, pl1);
      split_pk(mvA[4], mvA[5], ph2, pl2);
      BinA.u[0] = (g & 1) ? pl0 : ph0;
      BinA.u[1] = (g & 1) ? pl1 : ph1;
      BinA.u[2] = (g & 1) ? pl2 : ph2;
      BinA.u[3] = bias_word;
      split_pk(mvB[0], mvB[1], ph0, pl0);
      split_pk(mvB[2], mvB[3], ph1, pl1);
      split_pk(mvB[4], mvB[5], ph2, pl2);
      BinB.u[0] = (g & 1) ? pl0 : ph0;
      BinB.u[1] = (g & 1) ? pl1 : ph1;
      BinB.u[2] = (g & 1) ? pl2 : ph2;
      BinB.u[3] = bias_word;
    }

    // input layer: 2 MFMAs per tile, interleaved A/B chains
    f32x4 dT0A = __builtin_amdgcn_mfma_f32_16x16x32_bf16(AW[0], BinA.v, z, 0, 0, 0);
    f32x4 dT0B = __builtin_amdgcn_mfma_f32_16x16x32_bf16(AW[0], BinB.v, z, 0, 0, 0);
    f32x4 dT1A = __builtin_amdgcn_mfma_f32_16x16x32_bf16(AW[1], BinA.v, z, 0, 0, 0);
    f32x4 dT1B = __builtin_amdgcn_mfma_f32_16x16x32_bf16(AW[1], BinB.v, z, 0, 0, 0);

    bf16x8 BhA, BlA, BhB, BlB;
    refrag_ll(dT0A, dT1A, BhA, BlA);
    refrag_ll(dT0B, dT1B, BhB, BlB);

#pragma unroll
    for (int d = 0; d < 3; ++d) {
      dT0A = __builtin_amdgcn_mfma_f32_16x16x32_bf16(AhW[d][0], BhA, z, 0, 0, 0);
      dT0B = __builtin_amdgcn_mfma_f32_16x16x32_bf16(AhW[d][0], BhB, z, 0, 0, 0);
      dT1A = __builtin_amdgcn_mfma_f32_16x16x32_bf16(AhW[d][1], BhA, z, 0, 0, 0);
      dT1B = __builtin_amdgcn_mfma_f32_16x16x32_bf16(AhW[d][1], BhB, z, 0, 0, 0);
      dT0A = __builtin_amdgcn_mfma_f32_16x16x32_bf16(AlW[d][0], BhA, dT0A, 0, 0, 0);
      dT0B = __builtin_amdgcn_mfma_f32_16x16x32_bf16(AlW[d][0], BhB, dT0B, 0, 0, 0);
      dT1A = __builtin_amdgcn_mfma_f32_16x16x32_bf16(AlW[d][1], BhA, dT1A, 0, 0, 0);
      dT1B = __builtin_amdgcn_mfma_f32_16x16x32_bf16(AlW[d][1], BhB, dT1B, 0, 0, 0);
      dT0A = __builtin_amdgcn_mfma_f32_16x16x32_bf16(AhW[d][0], BlA, dT0A, 0, 0, 0);
      dT0B = __builtin_amdgcn_mfma_f32_16x16x32_bf16(AhW[d][0], BlB, dT0B, 0, 0, 0);
      dT1A = __builtin_amdgcn_mfma_f32_16x16x32_bf16(AhW[d][1], BlA, dT1A, 0, 0, 0);
      dT1B = __builtin_amdgcn_mfma_f32_16x16x32_bf16(AhW[d][1], BlB, dT1B, 0, 0, 0);
      if (d < 2) {
        refrag_br(dT0A, dT1A, bsA[d], bsB[d], BhA, BlA);
        refrag_br(dT0B, dT1B, bsA[d], bsB[d], BhB, BlB);
      } else {
        float sumA = 0.f, sumB = 0.f;
#pragma unroll
        for (int r = 0; r < 4; ++r) {
          sumA = fmaf(fmaxf(dT0A[r] + bsA[2][r], 0.f), woA[r], sumA);
          sumA = fmaf(fmaxf(dT1A[r] + bsB[2][r], 0.f), woB[r], sumA);
          sumB = fmaf(fmaxf(dT0B[r] + bsA[2][r], 0.f), woA[r], sumB);
          sumB = fmaf(fmaxf(dT1B[r] + bsB[2][r], 0.f), woB[r], sumB);
        }
        sumA += __shfl_xor(sumA, 16);
        sumA += __shfl_xor(sumA, 32);
        sumB += __shfl_xor(sumB, 16);
        sumB += __shfl_xor(sumB, 32);
        if (g == 0) {
          out[tbA + c] = mkA ? (sumA + bo) : 0.0f;
          out[tbB + c] = mkB ? (sumB + bo) : 0.0f;
        }
      }
    }

#pragma unroll
    for (int i = 0; i < 6; ++i) { mvA[i] = nvA[i]; mvB[i] = nvB[i]; }
    mkA = nkA; mkB = nkB;
  }
}

extern "C" void kernel_launch(void* const* d_in, const int* in_sizes, int n_in,
                              void* d_out, int out_size, void* d_ws, size_t ws_size,
                              hipStream_t stream) {
  const float* Imodel   = (const float*)d_in[0];
  const float* Iobs     = (const float*)d_in[1];
  const float* metadata = (const float*)d_in[2];
  const void*  mask     = d_in[3];
  const int*   sample_size = (const int*)d_in[4];
  const float* W_img_in = (const float*)d_in[5];
  const float* b_img_in = (const float*)d_in[6];
  const float* W_img    = (const float*)d_in[7];
  const float* b_img    = (const float*)d_in[8];
  const float* W_lin_in = (const float*)d_in[9];
  const float* b_lin_in = (const float*)d_in[10];
  const float* W_mlp    = (const float*)d_in[11];
  const float* b_mlp    = (const float*)d_in[12];
  const float* W_out    = (const float*)d_in[13];
  const float* b_out    = (const float*)d_in[14];
  float* out = (float*)d_out;

  char* ws = (char*)d_ws;
  int*   flag     = (int*)(ws + WS_FLAG);
  int*   sel      = (int*)(ws + WS_SEL);
  int*   vint     = (int*)(ws + WS_VINT);
  int*   vbyte    = (int*)(ws + WS_VBYTE);
  float* partial  = (float*)(ws + WS_PART);
  float* rep_bias = (float*)(ws + WS_REPB);

  k_valid<<<NROW / 4, 256, 0, stream>>>(mask, vint, vbyte);
  k_select<<<BB, 64, 0, stream>>>(mask, vint, vbyte, sample_size, flag, sel);
  k_image<<<512, 256, 0, stream>>>(Imodel, Iobs, metadata, mask, flag, sel,
                                   sample_size, W_img_in, b_img_in, W_img,
                                   b_img, partial);
  k_rep<<<BB, 32, 0, stream>>>(partial, b_lin_in, rep_bias);
  k_scale<<<1536, 256, 0, stream>>>(metadata, mask, flag, W_lin_in, rep_bias,
                                    W_mlp, b_mlp, W_out, b_out, out);
}